// Round 10
// baseline (221.188 us; speedup 1.0000x reference)
//
#include <hip/hip_runtime.h>
#include <hip/hip_bf16.h>

typedef _Float16 h8 __attribute__((ext_vector_type(8)));
typedef float f4 __attribute__((ext_vector_type(4)));

#define N_TOK 65536
#define DIM 256
#define KCODES 1024
#define HWSZ 4096
#define TAU 0.75f
#define FCAP 16384

// async global->LDS, 16B per lane. LDS dest = wave-uniform base + lane*16.
__device__ __forceinline__ void gll16(const void* g, void* l) {
    __builtin_amdgcn_global_load_lds((const __attribute__((address_space(1))) void*)g,
                                     (__attribute__((address_space(3))) void*)l, 16, 0, 0);
}

// Fragment layout: element (n,d) -> granule G = ((n>>4)*8+(d>>5))*64 + ((d>>3)&3)*16 + (n&15)

// ---------------- K0a: embedding -> fragment-layout fp16 hi/lo ---------------
__global__ void k_prep_frag(const float* __restrict__ emb, _Float16* __restrict__ BhF,
                            _Float16* __restrict__ BlF) {
    int gi = blockIdx.x * 256 + threadIdx.x;
    int kb = gi >> 9, s = (gi >> 6) & 7, dq = (gi >> 4) & 3, r = gi & 15;
    int code = kb * 16 + r;
    const float* src = emb + (size_t)code * DIM + s * 32 + dq * 8;
    float4 x0 = *(const float4*)(src);
    float4 x1 = *(const float4*)(src + 4);
    float xs[8] = {x0.x, x0.y, x0.z, x0.w, x1.x, x1.y, x1.z, x1.w};
    h8 hi, lo;
#pragma unroll
    for (int j = 0; j < 8; ++j) {
        _Float16 h = (_Float16)xs[j];
        hi[j] = h;
        lo[j] = (_Float16)(xs[j] - (float)h);
    }
    *(h8*)(BhF + (size_t)gi * 8) = hi;
    *(h8*)(BlF + (size_t)gi * 8) = lo;
}

// ---------------- K0b: e_sq + zero flag counter ------------------------------
__global__ void k_esq(const float* __restrict__ emb, float* __restrict__ e_sq,
                      int* __restrict__ flagCnt) {
    if (blockIdx.x == 0 && threadIdx.x == 0) *flagCnt = 0;
    int t = threadIdx.x;
    int code = blockIdx.x * 4 + (t >> 6);
    int l = t & 63;
    float4 v = *(const float4*)(emb + (size_t)code * DIM + l * 4);
    float s = v.x * v.x + v.y * v.y + v.z * v.z + v.w * v.w;
#pragma unroll
    for (int off = 32; off >= 1; off >>= 1) s += __shfl_xor(s, off);
    if (l == 0) e_sq[code] = s;
}

// ------- K1: transpose z[B,C,H,W] -> enc[N,C] + fragment fp16 hi only --------
__global__ void k_transpose(const float* __restrict__ z, float* __restrict__ enc,
                            _Float16* __restrict__ AhF) {
    __shared__ float T[64][65];
    int blk = blockIdx.x;
    int b = blk >> 8;
    int rem = blk & 255;
    int c0 = (rem >> 6) * 64;
    int hw0 = (rem & 63) * 64;
    int t = threadIdx.x;
    const float* zp = z + (size_t)b * DIM * HWSZ;
    {
        int hw4 = (t & 15) * 4, cl = t >> 4;
#pragma unroll
        for (int i = 0; i < 4; ++i) {
            int c = cl + i * 16;
            float4 v = *(const float4*)(zp + (size_t)(c0 + c) * HWSZ + hw0 + hw4);
            T[c][hw4 + 0] = v.x; T[c][hw4 + 1] = v.y;
            T[c][hw4 + 2] = v.z; T[c][hw4 + 3] = v.w;
        }
    }
    __syncthreads();
    {
        int c4 = (t & 15) * 4, hwl = t >> 4;
#pragma unroll
        for (int i = 0; i < 4; ++i) {
            int hw = hwl + i * 16;
            float4 v;
            v.x = T[c4 + 0][hw]; v.y = T[c4 + 1][hw];
            v.z = T[c4 + 2][hw]; v.w = T[c4 + 3][hw];
            *(float4*)(enc + (size_t)(b * HWSZ + hw0 + hw) * DIM + c0 + c4) = v;
        }
    }
    {
        int base_nb = b * 256 + (hw0 >> 4);
#pragma unroll
        for (int i = 0; i < 2; ++i) {
            int gidx = i * 256 + t;
            int nbi = gidx >> 7, si = (gidx >> 6) & 1, dq = (gidx >> 4) & 3, r = gidx & 15;
            int hwl = nbi * 16 + r;
            int cl = si * 32 + dq * 8;
            h8 hi;
#pragma unroll
            for (int j = 0; j < 8; ++j) hi[j] = (_Float16)T[cl + j][hwl];
            size_t G = (((size_t)(base_nb + nbi) * 8) + (c0 >> 5) + si) * 64 + dq * 16 + r;
            *(h8*)(AhF + G * 8) = hi;
        }
    }
}

#define WAITV(n) asm volatile("s_waitcnt vmcnt(" #n ")" ::: "memory")
#define BARRIER __builtin_amdgcn_s_barrier()
#define PRIO1 __builtin_amdgcn_s_setprio(1)
#define PRIO0 __builtin_amdgcn_s_setprio(0)

extern __shared__ char SB[];   // 4 bufs x 32 KB; fold scratch overlays buf0

// ---- K2: pass-1 GEMM (hh only) + top-2 argmin, rchunk-major grid ------------
__global__ __launch_bounds__(1024)
void k_gemm1(const _Float16* __restrict__ AhF, const _Float16* __restrict__ BhF,
             const float* __restrict__ e_sq,
             float* __restrict__ pV1, int* __restrict__ pI1, float* __restrict__ pV2) {
    int gid = blockIdx.x;
    int grp = gid >> 7;
    int colTile = (gid >> 5) & 3;
    int rowTile = grp * 32 + (gid & 31);
    int r0 = rowTile * 256, c0 = colTile * 256;
    int t = threadIdx.x;
    int w = t >> 6, l = t & 63;
    int wm = w >> 2, wn = w & 3;
    int l16 = l & 15, lhi = l >> 4;

    const char* gAh = (const char*)AhF + (((size_t)(rowTile * 16 + w)) << 13) + (l << 4);
    const char* gBh = (const char*)BhF + (((size_t)(colTile * 16 + w)) << 13) + (l << 4);

#define ISSUE1(p) do { \
    char* bp_ = SB + ((p) & 3) * 32768; \
    gll16(gAh + ((p) << 10), bp_ + (w << 10)); \
    gll16(gBh + ((p) << 10), bp_ + 16384 + (w << 10)); \
} while (0)

#define PHASE1(q, W, DO_ISSUE) { \
    WAITV(W); \
    BARRIER; \
    if (DO_ISSUE) ISSUE1((q) + 3); \
    const char* bp_ = SB + ((q) & 3) * 32768; \
    h8 ah[4], bh[4]; \
    _Pragma("unroll") for (int mf = 0; mf < 4; ++mf) \
        ah[mf] = *(const h8*)(bp_ + ((wm * 4 + mf) << 10) + (l << 4)); \
    _Pragma("unroll") for (int nf = 0; nf < 4; ++nf) \
        bh[nf] = *(const h8*)(bp_ + 16384 + ((wn * 4 + nf) << 10) + (l << 4)); \
    PRIO1; \
    _Pragma("unroll") for (int mf = 0; mf < 4; ++mf) \
        _Pragma("unroll") for (int nf = 0; nf < 4; ++nf) \
            acc[mf][nf] = __builtin_amdgcn_mfma_f32_16x16x32_f16(ah[mf], bh[nf], acc[mf][nf], 0, 0, 0); \
    PRIO0; }

    f4 acc[4][4];
#pragma unroll
    for (int i = 0; i < 4; ++i)
#pragma unroll
        for (int j = 0; j < 4; ++j) acc[i][j] = (f4)0.0f;

    ISSUE1(0); ISSUE1(1); ISSUE1(2);

    PHASE1(0, 4, 1)  PHASE1(1, 4, 1)  PHASE1(2, 4, 1)  PHASE1(3, 4, 1)
    PHASE1(4, 4, 1)  PHASE1(5, 4, 0)  PHASE1(6, 2, 0)  PHASE1(7, 0, 0)

    // ---- top-2 per-row argmin over this block's 256 codes ----
    float* smV1 = (float*)SB;             // [4][256]
    int*   smI1 = (int*)(SB + 4096);
    float* smV2 = (float*)(SB + 8192);

    float esq[4];
#pragma unroll
    for (int nf = 0; nf < 4; ++nf) esq[nf] = e_sq[c0 + wn * 64 + nf * 16 + l16];

#pragma unroll
    for (int mf = 0; mf < 4; ++mf) {
#pragma unroll
        for (int rg = 0; rg < 4; ++rg) {
            float v1 = 3.4e38f, v2 = 3.4e38f;
            int i1 = 0;
#pragma unroll
            for (int nf = 0; nf < 4; ++nf) {
                float v = esq[nf] - 2.0f * acc[mf][nf][rg];
                int ci = c0 + wn * 64 + nf * 16 + l16;
                if (v < v1 || (v == v1 && ci < i1)) { v2 = v1; v1 = v; i1 = ci; }
                else v2 = fminf(v2, v);
            }
#pragma unroll
            for (int off = 1; off < 16; off <<= 1) {
                float ov1 = __shfl_xor(v1, off);
                int oi1 = __shfl_xor(i1, off);
                float ov2 = __shfl_xor(v2, off);
                if (ov1 < v1 || (ov1 == v1 && oi1 < i1)) { v2 = fminf(v1, ov2); v1 = ov1; i1 = oi1; }
                else v2 = fminf(v2, ov1);
            }
            if (l16 == 0) {
                int rloc = wm * 64 + mf * 16 + lhi * 4 + rg;
                smV1[wn * 256 + rloc] = v1;
                smI1[wn * 256 + rloc] = i1;
                smV2[wn * 256 + rloc] = v2;
            }
        }
    }
    __syncthreads();
    if (t < 256) {
        float v1 = smV1[t], v2 = smV2[t];
        int i1 = smI1[t];
#pragma unroll
        for (int wn2 = 1; wn2 < 4; ++wn2) {
            float a1 = smV1[wn2 * 256 + t];
            int ai = smI1[wn2 * 256 + t];
            float a2 = smV2[wn2 * 256 + t];
            if (a1 < v1 || (a1 == v1 && ai < i1)) { v2 = fminf(v1, a2); v1 = a1; i1 = ai; }
            else v2 = fminf(v2, a1);
        }
        pV1[colTile * N_TOK + r0 + t] = v1;
        pI1[colTile * N_TOK + r0 + t] = i1;
        pV2[colTile * N_TOK + r0 + t] = v2;
    }
}

// ---- K3: combine partials -> index, flag ambiguous, gather out1 -------------
__global__ void k_final_flag(const float* __restrict__ pV1, const int* __restrict__ pI1,
                             const float* __restrict__ pV2, const float* __restrict__ emb,
                             float* __restrict__ out2, int* __restrict__ idxI,
                             int* __restrict__ flagCnt, int* __restrict__ flagList,
                             float* __restrict__ out1) {
    __shared__ int sidx[256];
    int t = threadIdx.x;
    int n0 = blockIdx.x * 256;
    int n = n0 + t;
    float v1 = pV1[n], v2 = pV2[n];
    int i1 = pI1[n];
#pragma unroll
    for (int ct = 1; ct < 4; ++ct) {
        float a1 = pV1[ct * N_TOK + n];
        int ai = pI1[ct * N_TOK + n];
        float a2 = pV2[ct * N_TOK + n];
        if (a1 < v1 || (a1 == v1 && ai < i1)) { v2 = fminf(v1, a2); v1 = a1; i1 = ai; }
        else v2 = fminf(v2, a1);
    }
    out2[n] = (float)i1;
    idxI[n] = i1;
    sidx[t] = i1;
    if (v2 - v1 < TAU) {
        int p = atomicAdd(flagCnt, 1);
        if (p < FCAP) flagList[p] = n;
    }
    __syncthreads();
    int rr = t >> 2, q = t & 3;
#pragma unroll
    for (int i = 0; i < 4; ++i) {
        int r = i * 64 + rr;
        int idx = sidx[r];
        const float* src = emb + (size_t)idx * DIM + q * 64;
        float* dst = out1 + (size_t)(n0 + r) * DIM + q * 64;
#pragma unroll
        for (int j = 0; j < 16; ++j)
            *(float4*)(dst + j * 4) = *(const float4*)(src + j * 4);
    }
}

// ---- K4: gather flagged rows -> compact fragment-layout hi/lo ---------------
__global__ void k_gather_split(const float* __restrict__ enc, const int* __restrict__ flagCnt,
                               const int* __restrict__ flagList,
                               _Float16* __restrict__ AhC, _Float16* __restrict__ AlC) {
    __shared__ int rows[16];
    int Fc = *flagCnt; if (Fc > FCAP) Fc = FCAP;
    int j0 = blockIdx.x * 16;
    if (j0 >= Fc || Fc == 0) return;
    int t = threadIdx.x;
    if (t < 16) {
        int j = j0 + t;
        rows[t] = flagList[j < Fc ? j : Fc - 1];
    }
    __syncthreads();
#pragma unroll
    for (int i = 0; i < 2; ++i) {
        int g = i * 256 + t;
        int s = g >> 6, dq = (g >> 4) & 3, r = g & 15;
        int row = rows[r];
        const float* src = enc + (size_t)row * DIM + s * 32 + dq * 8;
        float4 x0 = *(const float4*)(src);
        float4 x1 = *(const float4*)(src + 4);
        float xs[8] = {x0.x, x0.y, x0.z, x0.w, x1.x, x1.y, x1.z, x1.w};
        h8 hi, lo;
#pragma unroll
        for (int j = 0; j < 8; ++j) {
            _Float16 h = (_Float16)xs[j];
            hi[j] = h;
            lo[j] = (_Float16)(xs[j] - (float)h);
        }
        size_t G = ((size_t)(blockIdx.x * 8 + s)) * 64 + dq * 16 + r;
        *(h8*)(AhC + G * 8) = hi;
        *(h8*)(AlC + G * 8) = lo;
    }
}

// ---- K5: exact-enough 3-pass rescore GEMM on compact flagged rows -----------
__global__ __launch_bounds__(1024)
void k_rescore3(const _Float16* __restrict__ AhC, const _Float16* __restrict__ AlC,
                const _Float16* __restrict__ BhF, const _Float16* __restrict__ BlF,
                const float* __restrict__ e_sq, const int* __restrict__ flagCnt,
                float* __restrict__ pVr, int* __restrict__ pIr) {
    int Fc = *flagCnt; if (Fc > FCAP) Fc = FCAP;
    int gid = blockIdx.x;
    int colTile = gid & 3, rowTile = gid >> 2;
    if (rowTile * 256 >= Fc) return;
    int r0 = rowTile * 256, c0 = colTile * 256;
    int t = threadIdx.x;
    int w = t >> 6, l = t & 63;
    int wm = w >> 2, wn = w & 3;
    int l16 = l & 15, lhi = l >> 4;

    const char* gAh = (const char*)AhC + (((size_t)(rowTile * 16 + w)) << 13) + (l << 4);
    const char* gAl = (const char*)AlC + (((size_t)(rowTile * 16 + w)) << 13) + (l << 4);
    const char* gBh = (const char*)BhF + (((size_t)(colTile * 16 + w)) << 13) + (l << 4);
    const char* gBl = (const char*)BlF + (((size_t)(colTile * 16 + w)) << 13) + (l << 4);

#define ISSUE_P(p) do { \
    const int s_ = (p) >> 1; \
    char* bp_ = SB + ((p) & 3) * 32768; \
    const char* a_ = ((p) & 1) ? gAl : gAh; \
    const char* b_ = ((p) & 1) ? gBl : gBh; \
    gll16(a_ + (s_ << 10), bp_ + (w << 10)); \
    gll16(b_ + (s_ << 10), bp_ + 16384 + (w << 10)); \
} while (0)

#define MFMA16(A_, B_) { _Pragma("unroll") for (int mf = 0; mf < 4; ++mf) \
    _Pragma("unroll") for (int nf = 0; nf < 4; ++nf) \
        acc[mf][nf] = __builtin_amdgcn_mfma_f32_16x16x32_f16(A_[mf], B_[nf], acc[mf][nf], 0, 0, 0); }

#define PHASE(q, W, DO_ISSUE) { \
    WAITV(W); \
    BARRIER; \
    if (DO_ISSUE) ISSUE_P((q) + 3); \
    const char* bp_ = SB + ((q) & 3) * 32768; \
    if (((q) & 1) == 0) { \
        _Pragma("unroll") for (int mf = 0; mf < 4; ++mf) \
            ah[mf] = *(const h8*)(bp_ + ((wm * 4 + mf) << 10) + (l << 4)); \
        _Pragma("unroll") for (int nf = 0; nf < 4; ++nf) \
            bh[nf] = *(const h8*)(bp_ + 16384 + ((wn * 4 + nf) << 10) + (l << 4)); \
        PRIO1; MFMA16(ah, bh); PRIO0; \
    } else { \
        h8 xl[4]; \
        _Pragma("unroll") for (int nf = 0; nf < 4; ++nf) \
            xl[nf] = *(const h8*)(bp_ + 16384 + ((wn * 4 + nf) << 10) + (l << 4)); \
        PRIO1; MFMA16(ah, xl); PRIO0; \
        _Pragma("unroll") for (int mf = 0; mf < 4; ++mf) \
            xl[mf] = *(const h8*)(bp_ + ((wm * 4 + mf) << 10) + (l << 4)); \
        PRIO1; MFMA16(xl, bh); PRIO0; \
    } }

    f4 acc[4][4];
#pragma unroll
    for (int i = 0; i < 4; ++i)
#pragma unroll
        for (int j = 0; j < 4; ++j) acc[i][j] = (f4)0.0f;

    h8 ah[4], bh[4];

    ISSUE_P(0); ISSUE_P(1); ISSUE_P(2);

    PHASE(0, 4, 1)   PHASE(1, 4, 1)   PHASE(2, 4, 1)   PHASE(3, 4, 1)
    PHASE(4, 4, 1)   PHASE(5, 4, 1)   PHASE(6, 4, 1)   PHASE(7, 4, 1)
    PHASE(8, 4, 1)   PHASE(9, 4, 1)   PHASE(10, 4, 1)  PHASE(11, 4, 1)
    PHASE(12, 4, 1)  PHASE(13, 4, 0)  PHASE(14, 2, 0)  PHASE(15, 0, 0)

    float* smV = (float*)SB;
    int* smI = (int*)(SB + 4096);

    float esq[4];
#pragma unroll
    for (int nf = 0; nf < 4; ++nf) esq[nf] = e_sq[c0 + wn * 64 + nf * 16 + l16];

#pragma unroll
    for (int mf = 0; mf < 4; ++mf) {
#pragma unroll
        for (int rg = 0; rg < 4; ++rg) {
            float bestV = 3.4e38f;
            int bestI = 0;
#pragma unroll
            for (int nf = 0; nf < 4; ++nf) {
                float v = esq[nf] - 2.0f * acc[mf][nf][rg];
                int ci = c0 + wn * 64 + nf * 16 + l16;
                if (v < bestV || (v == bestV && ci < bestI)) { bestV = v; bestI = ci; }
            }
#pragma unroll
            for (int off = 1; off < 16; off <<= 1) {
                float vv = __shfl_xor(bestV, off);
                int ii = __shfl_xor(bestI, off);
                if (vv < bestV || (vv == bestV && ii < bestI)) { bestV = vv; bestI = ii; }
            }
            if (l16 == 0) {
                int rloc = wm * 64 + mf * 16 + lhi * 4 + rg;
                smV[wn * 256 + rloc] = bestV;
                smI[wn * 256 + rloc] = bestI;
            }
        }
    }
    __syncthreads();
    if (t < 256) {
        float bestV = smV[t];
        int bestI = smI[t];
#pragma unroll
        for (int wn2 = 1; wn2 < 4; ++wn2) {
            float v = smV[wn2 * 256 + t];
            int i2 = smI[wn2 * 256 + t];
            if (v < bestV || (v == bestV && i2 < bestI)) { bestV = v; bestI = i2; }
        }
        pVr[colTile * FCAP + r0 + t] = bestV;
        pIr[colTile * FCAP + r0 + t] = bestI;
    }
}

// ---- K6: finalize rescored rows: update out2/idxI/out1 ----------------------
__global__ void k_rescore_final(const float* __restrict__ pVr, const int* __restrict__ pIr,
                                const int* __restrict__ flagCnt, const int* __restrict__ flagList,
                                const float* __restrict__ emb,
                                float* __restrict__ out2, int* __restrict__ idxI,
                                float* __restrict__ out1) {
    __shared__ int sfi[64];
    int Fc = *flagCnt; if (Fc > FCAP) Fc = FCAP;
    int j0 = blockIdx.x * 64;
    if (j0 >= Fc) return;
    int t = threadIdx.x;
    if (t < 64) {
        int j = j0 + t;
        int fi = 0;
        if (j < Fc) {
            float fv = pVr[j];
            fi = pIr[j];
#pragma unroll
            for (int ct = 1; ct < 4; ++ct) {
                float a = pVr[ct * FCAP + j];
                int ai = pIr[ct * FCAP + j];
                if (a < fv || (a == fv && ai < fi)) { fv = a; fi = ai; }
            }
            int row = flagList[j];
            out2[row] = (float)fi;
            idxI[row] = fi;
        }
        sfi[t] = fi;
    }
    __syncthreads();
    int j = j0 + (t >> 2);
    if (j < Fc) {
        int row = flagList[j];
        int fi = sfi[t >> 2];
        int q = t & 3;
        const float* src = emb + (size_t)fi * DIM + q * 64;
        float* dst = out1 + (size_t)row * DIM + q * 64;
#pragma unroll
        for (int i = 0; i < 16; ++i)
            *(float4*)(dst + i * 4) = *(const float4*)(src + i * 4);
    }
}

// ---------------- K7: quantized[B,C,H,W] via LDS transpose -------------------
__global__ void k_out3(const float* __restrict__ emb, const int* __restrict__ idxI,
                       float* __restrict__ out3) {
    __shared__ float E[32][257];
    int blk = blockIdx.x;
    int b = blk >> 7, hwt = blk & 127;
    int hw0 = hwt * 32;
    int n0 = b * HWSZ + hw0;
    int t = threadIdx.x;
    {
        int r = t >> 3, oct = t & 7;
        int idx = idxI[n0 + r];
        const float* src = emb + (size_t)idx * DIM + oct * 32;
#pragma unroll
        for (int i = 0; i < 8; ++i) {
            float4 v = *(const float4*)(src + i * 4);
            E[r][oct * 32 + i * 4 + 0] = v.x;
            E[r][oct * 32 + i * 4 + 1] = v.y;
            E[r][oct * 32 + i * 4 + 2] = v.z;
            E[r][oct * 32 + i * 4 + 3] = v.w;
        }
    }
    __syncthreads();
    {
        int w = t >> 6, l = t & 63;
        int ch = l >> 5, hw = l & 31;
        float* dst = out3 + (size_t)b * DIM * HWSZ + hw0 + hw;
#pragma unroll
        for (int it = 0; it < 32; ++it) {
            int c = w * 64 + it * 2 + ch;
            dst[(size_t)c * HWSZ] = E[hw][c];
        }
    }
}

extern "C" void kernel_launch(void* const* d_in, const int* in_sizes, int n_in,
                              void* d_out, int out_size, void* d_ws, size_t ws_size,
                              hipStream_t stream) {
    const float* z = (const float*)d_in[0];
    const float* emb = (const float*)d_in[1];
    float* out = (float*)d_out;
    float* out0 = out;                    // encoded_flat  [65536,256]
    float* out1 = out + 16777216;         // quantized_flat[65536,256]
    float* out2 = out + 33554432;         // indices       [65536] (as float)
    float* out3 = out + 33619968;         // quantized     [16,256,64,64]

    // AhF (32 MB) in out1 region: read by k_gemm1, then out1 overwritten by
    // k_final_flag / k_rescore_final.
    _Float16* AhF = (_Float16*)out1;

    // out3 region (64 MB) holds: AhC/AlC compact (8+8 MB), pass-1 partials
    // (3 MB), rescore partials (0.5 MB). k_out3 writes out3 last.
    char* o3 = (char*)out3;
    _Float16* AhC = (_Float16*)(o3);                  // 8 MB  (FCAP*256*2B)
    _Float16* AlC = (_Float16*)(o3 + 8388608);        // 8 MB
    float* pV1 = (float*)(o3 + 16777216);             // 1 MB
    int*   pI1 = (int*)  (o3 + 17825792);             // 1 MB
    float* pV2 = (float*)(o3 + 18874368);             // 1 MB
    float* pVr = (float*)(o3 + 19922944);             // 256 KB
    int*   pIr = (int*)  (o3 + 20185088);             // 256 KB

    char* ws = (char*)d_ws;
    _Float16* BhF = (_Float16*)(ws);                  // 512 KB
    _Float16* BlF = (_Float16*)(ws + 524288);         // 512 KB
    float* e_sq = (float*)(ws + 1048576);             // 4 KB
    int* flagCnt = (int*)(ws + 1052672);              // 4 KB slot
    int* flagList = (int*)(ws + 1056768);             // 64 KB
    int* idxI = (int*)(ws + 1121280);                 // 256 KB

    hipFuncSetAttribute((const void*)k_gemm1,
                        hipFuncAttributeMaxDynamicSharedMemorySize, 131072);
    hipFuncSetAttribute((const void*)k_rescore3,
                        hipFuncAttributeMaxDynamicSharedMemorySize, 131072);

    k_prep_frag<<<128, 256, 0, stream>>>(emb, BhF, BlF);
    k_esq<<<256, 256, 0, stream>>>(emb, e_sq, flagCnt);
    k_transpose<<<4096, 256, 0, stream>>>(z, out0, AhF);
    k_gemm1<<<1024, 1024, 131072, stream>>>(AhF, BhF, e_sq, pV1, pI1, pV2);
    k_final_flag<<<256, 256, 0, stream>>>(pV1, pI1, pV2, emb, out2, idxI,
                                          flagCnt, flagList, out1);
    k_gather_split<<<1024, 256, 0, stream>>>(out0, flagCnt, flagList, AhC, AlC);
    k_rescore3<<<1024, 1024, 131072, stream>>>(AhC, AlC, BhF, BlF, e_sq, flagCnt,
                                               pVr, pIr);
    k_rescore_final<<<256, 256, 0, stream>>>(pVr, pIr, flagCnt, flagList, emb,
                                             out2, idxI, out1);
    k_out3<<<2048, 256, 0, stream>>>(emb, idxI, out3);
}

// Round 11
// 205.479 us; speedup vs baseline: 1.0764x; 1.0764x over previous
//
#include <hip/hip_runtime.h>
#include <hip/hip_bf16.h>

typedef _Float16 h8 __attribute__((ext_vector_type(8)));
typedef float f4 __attribute__((ext_vector_type(4)));

#define N_TOK 65536
#define DIM 256
#define KCODES 1024
#define HWSZ 4096

// async global->LDS, 16B per lane. LDS dest = wave-uniform base + lane*16.
__device__ __forceinline__ void gll16(const void* g, void* l) {
    __builtin_amdgcn_global_load_lds((const __attribute__((address_space(1))) void*)g,
                                     (__attribute__((address_space(3))) void*)l, 16, 0, 0);
}

// Fragment layout (A and B operands, 16x16x32 f16 MFMA):
//   element (n, d) -> granule G = ((n>>4)*8 + (d>>5))*64 + ((d>>3)&3)*16 + (n&15),
//   half j = d&7 inside the 16B granule. Conflict-free ds_read_b128, linear gll16.

// ---------------- K0a: embedding -> fragment-layout fp16 hi/lo ---------------
__global__ void k_prep_frag(const float* __restrict__ emb, _Float16* __restrict__ BhF,
                            _Float16* __restrict__ BlF) {
    int gi = blockIdx.x * 256 + threadIdx.x;
    int kb = gi >> 9, s = (gi >> 6) & 7, dq = (gi >> 4) & 3, r = gi & 15;
    int code = kb * 16 + r;
    const float* src = emb + (size_t)code * DIM + s * 32 + dq * 8;
    float4 x0 = *(const float4*)(src);
    float4 x1 = *(const float4*)(src + 4);
    float xs[8] = {x0.x, x0.y, x0.z, x0.w, x1.x, x1.y, x1.z, x1.w};
    h8 hi, lo;
#pragma unroll
    for (int j = 0; j < 8; ++j) {
        _Float16 h = (_Float16)xs[j];
        hi[j] = h;
        lo[j] = (_Float16)(xs[j] - (float)h);
    }
    *(h8*)(BhF + (size_t)gi * 8) = hi;
    *(h8*)(BlF + (size_t)gi * 8) = lo;
}

// ---------------- K0b: e_sq ---------------------------------------------------
__global__ void k_esq(const float* __restrict__ emb, float* __restrict__ e_sq) {
    int t = threadIdx.x;
    int code = blockIdx.x * 4 + (t >> 6);
    int l = t & 63;
    float4 v = *(const float4*)(emb + (size_t)code * DIM + l * 4);
    float s = v.x * v.x + v.y * v.y + v.z * v.z + v.w * v.w;
#pragma unroll
    for (int off = 32; off >= 1; off >>= 1) s += __shfl_xor(s, off);
    if (l == 0) e_sq[code] = s;
}

// ------- K1: transpose z[B,C,H,W] -> enc[N,C] + fragment fp16 hi/lo ----------
__global__ void k_transpose(const float* __restrict__ z, float* __restrict__ enc,
                            _Float16* __restrict__ AhF, _Float16* __restrict__ AlF) {
    __shared__ float T[64][65];
    int blk = blockIdx.x;
    int b = blk >> 8;
    int rem = blk & 255;
    int c0 = (rem >> 6) * 64;
    int hw0 = (rem & 63) * 64;
    int t = threadIdx.x;
    const float* zp = z + (size_t)b * DIM * HWSZ;
    {
        int hw4 = (t & 15) * 4, cl = t >> 4;
#pragma unroll
        for (int i = 0; i < 4; ++i) {
            int c = cl + i * 16;
            float4 v = *(const float4*)(zp + (size_t)(c0 + c) * HWSZ + hw0 + hw4);
            T[c][hw4 + 0] = v.x; T[c][hw4 + 1] = v.y;
            T[c][hw4 + 2] = v.z; T[c][hw4 + 3] = v.w;
        }
    }
    __syncthreads();
    {
        int c4 = (t & 15) * 4, hwl = t >> 4;
#pragma unroll
        for (int i = 0; i < 4; ++i) {
            int hw = hwl + i * 16;
            float4 v;
            v.x = T[c4 + 0][hw]; v.y = T[c4 + 1][hw];
            v.z = T[c4 + 2][hw]; v.w = T[c4 + 3][hw];
            *(float4*)(enc + (size_t)(b * HWSZ + hw0 + hw) * DIM + c0 + c4) = v;
        }
    }
    {
        int base_nb = b * 256 + (hw0 >> 4);
#pragma unroll
        for (int i = 0; i < 2; ++i) {
            int gidx = i * 256 + t;
            int nbi = gidx >> 7, si = (gidx >> 6) & 1, dq = (gidx >> 4) & 3, r = gidx & 15;
            int hwl = nbi * 16 + r;
            int cl = si * 32 + dq * 8;
            h8 hi, lo;
#pragma unroll
            for (int j = 0; j < 8; ++j) {
                float x = T[cl + j][hwl];
                _Float16 h = (_Float16)x;
                hi[j] = h;
                lo[j] = (_Float16)(x - (float)h);
            }
            size_t G = (((size_t)(base_nb + nbi) * 8) + (c0 >> 5) + si) * 64 + dq * 16 + r;
            *(h8*)(AhF + G * 8) = hi;
            *(h8*)(AlF + G * 8) = lo;
        }
    }
}

// ---- K2: GEMM (fp16 split, 3 passes), merged-step phases, 2-step ring -------
#define WAITV(n) asm volatile("s_waitcnt vmcnt(" #n ")" ::: "memory")
#define BARRIER __builtin_amdgcn_s_barrier()
#define PRIO1 __builtin_amdgcn_s_setprio(1)
#define PRIO0 __builtin_amdgcn_s_setprio(0)

extern __shared__ char SB[];   // 2 step-bufs x 64 KB: [Ah 16K][Bh 16K][Al 16K][Bl 16K]

__global__ __launch_bounds__(1024)
void k_gemm_argmin(const _Float16* __restrict__ AhF, const _Float16* __restrict__ AlF,
                   const _Float16* __restrict__ BhF, const _Float16* __restrict__ BlF,
                   const float* __restrict__ e_sq,
                   float* __restrict__ pV1, int* __restrict__ pI1) {
    int gid = blockIdx.x;
    // rchunk-major: 8-MB A chunks (32 rowTiles) reused across all 4 colTiles
    int grp = gid >> 7;
    int colTile = (gid >> 5) & 3;
    int rowTile = grp * 32 + (gid & 31);
    int r0 = rowTile * 256, c0 = colTile * 256;
    int t = threadIdx.x;
    int w = t >> 6, l = t & 63;           // 16 waves
    int wm = w >> 2, wn = w & 3;          // wave tile 64x64
    int l16 = l & 15, lhi = l >> 4;

    const char* gAh = (const char*)AhF + (((size_t)(rowTile * 16 + w)) << 13) + (l << 4);
    const char* gAl = (const char*)AlF + (((size_t)(rowTile * 16 + w)) << 13) + (l << 4);
    const char* gBh = (const char*)BhF + (((size_t)(colTile * 16 + w)) << 13) + (l << 4);
    const char* gBl = (const char*)BlF + (((size_t)(colTile * 16 + w)) << 13) + (l << 4);

// stage all 4 operand chunks of K-step s into ring buf s&1 (4 KB per wave)
#define ISSUE_S(s) do { \
    char* bp_ = SB + ((s) & 1) * 65536; \
    gll16(gAh + ((s) << 10), bp_ + (w << 10)); \
    gll16(gBh + ((s) << 10), bp_ + 16384 + (w << 10)); \
    gll16(gAl + ((s) << 10), bp_ + 32768 + (w << 10)); \
    gll16(gBl + ((s) << 10), bp_ + 49152 + (w << 10)); \
} while (0)

#define MFMA16(A_, B_) { _Pragma("unroll") for (int mf = 0; mf < 4; ++mf) \
    _Pragma("unroll") for (int nf = 0; nf < 4; ++nf) \
        acc[mf][nf] = __builtin_amdgcn_mfma_f32_16x16x32_f16(A_[mf], B_[nf], acc[mf][nf], 0, 0, 0); }

// one K-step: hh burst, then (bl read + hl burst), then (al read + lh burst).
// WAITV(0) drains this step's 4 loads (issued one full phase ago); single barrier.
#define PHASE(q, DO_ISSUE) { \
    WAITV(0); \
    BARRIER; \
    if (DO_ISSUE) ISSUE_S((q) + 1); \
    const char* bp_ = SB + ((q) & 1) * 65536; \
    _Pragma("unroll") for (int mf = 0; mf < 4; ++mf) \
        ah[mf] = *(const h8*)(bp_ + ((wm * 4 + mf) << 10) + (l << 4)); \
    _Pragma("unroll") for (int nf = 0; nf < 4; ++nf) \
        bh[nf] = *(const h8*)(bp_ + 16384 + ((wn * 4 + nf) << 10) + (l << 4)); \
    PRIO1; MFMA16(ah, bh); PRIO0; \
    { h8 xl[4]; \
      _Pragma("unroll") for (int nf = 0; nf < 4; ++nf) \
          xl[nf] = *(const h8*)(bp_ + 49152 + ((wn * 4 + nf) << 10) + (l << 4)); \
      PRIO1; MFMA16(ah, xl); PRIO0; \
      _Pragma("unroll") for (int mf = 0; mf < 4; ++mf) \
          xl[mf] = *(const h8*)(bp_ + 32768 + ((wm * 4 + mf) << 10) + (l << 4)); \
      PRIO1; MFMA16(xl, bh); PRIO0; } }

    f4 acc[4][4];
#pragma unroll
    for (int i = 0; i < 4; ++i)
#pragma unroll
        for (int j = 0; j < 4; ++j) acc[i][j] = (f4)0.0f;

    h8 ah[4], bh[4];

    ISSUE_S(0);   // prologue: step 0 in flight

    PHASE(0, 1)  PHASE(1, 1)  PHASE(2, 1)  PHASE(3, 1)
    PHASE(4, 1)  PHASE(5, 1)  PHASE(6, 1)  PHASE(7, 0)

    // ---- scores + per-row argmin over this block's 256 codes ----
    // scratch overlays ring buf 0 (phase 7 computed from buf 1)
    float* smV = (float*)SB;          // [4][256]
    int* smI = (int*)(SB + 4096);     // [4][256]

    float esq[4];
#pragma unroll
    for (int nf = 0; nf < 4; ++nf) esq[nf] = e_sq[c0 + wn * 64 + nf * 16 + l16];

#pragma unroll
    for (int mf = 0; mf < 4; ++mf) {
#pragma unroll
        for (int rg = 0; rg < 4; ++rg) {
            float bestV = 3.4e38f;
            int bestI = 0;
#pragma unroll
            for (int nf = 0; nf < 4; ++nf) {
                float v = esq[nf] - 2.0f * acc[mf][nf][rg];
                int ci = c0 + wn * 64 + nf * 16 + l16;
                if (v < bestV || (v == bestV && ci < bestI)) { bestV = v; bestI = ci; }
            }
#pragma unroll
            for (int off = 1; off < 16; off <<= 1) {
                float vv = __shfl_xor(bestV, off);
                int ii = __shfl_xor(bestI, off);
                if (vv < bestV || (vv == bestV && ii < bestI)) { bestV = vv; bestI = ii; }
            }
            if (l16 == 0) {
                int rloc = wm * 64 + mf * 16 + lhi * 4 + rg;
                smV[wn * 256 + rloc] = bestV;
                smI[wn * 256 + rloc] = bestI;
            }
        }
    }
    __syncthreads();
    if (t < 256) {
        float bestV = smV[t];
        int bestI = smI[t];
#pragma unroll
        for (int wn2 = 1; wn2 < 4; ++wn2) {
            float v = smV[wn2 * 256 + t];
            int i2 = smI[wn2 * 256 + t];
            if (v < bestV || (v == bestV && i2 < bestI)) { bestV = v; bestI = i2; }
        }
        pV1[colTile * N_TOK + r0 + t] = bestV;
        pI1[colTile * N_TOK + r0 + t] = bestI;
    }
}

// ---- K3: fused epilogue: combine -> out2, gather out1, transpose out3 -------
__global__ void k_final_all(const float* __restrict__ pV1, const int* __restrict__ pI1,
                            const float* __restrict__ emb,
                            float* __restrict__ out2, float* __restrict__ out1,
                            float* __restrict__ out3) {
    __shared__ int sidx[256];
    __shared__ float E[32][257];
    int t = threadIdx.x;
    int n0 = blockIdx.x * 256;
    int n = n0 + t;
    float v1 = pV1[n];
    int i1 = pI1[n];
#pragma unroll
    for (int ct = 1; ct < 4; ++ct) {
        float a1 = pV1[ct * N_TOK + n];
        int ai = pI1[ct * N_TOK + n];
        if (a1 < v1 || (a1 == v1 && ai < i1)) { v1 = a1; i1 = ai; }
    }
    out2[n] = (float)i1;
    sidx[t] = i1;
    __syncthreads();
    // out1: gather embedding rows
    {
        int rr = t >> 2, q = t & 3;
#pragma unroll
        for (int i = 0; i < 4; ++i) {
            int r = i * 64 + rr;
            int idx = sidx[r];
            const float* src = emb + (size_t)idx * DIM + q * 64;
            float* dst = out1 + (size_t)(n0 + r) * DIM + q * 64;
#pragma unroll
            for (int j = 0; j < 16; ++j)
                *(float4*)(dst + j * 4) = *(const float4*)(src + j * 4);
        }
    }
    // out3: transposed writes, 8 sub-chunks of 32 tokens
    int b = n0 >> 12;
    int hw0b = n0 & 4095;
    for (int sub = 0; sub < 8; ++sub) {
        __syncthreads();
        {
            int r = t >> 3, oct = t & 7;
            int idx = sidx[sub * 32 + r];
            const float* src = emb + (size_t)idx * DIM + oct * 32;
#pragma unroll
            for (int i = 0; i < 8; ++i) {
                float4 v = *(const float4*)(src + i * 4);
                E[r][oct * 32 + i * 4 + 0] = v.x;
                E[r][oct * 32 + i * 4 + 1] = v.y;
                E[r][oct * 32 + i * 4 + 2] = v.z;
                E[r][oct * 32 + i * 4 + 3] = v.w;
            }
        }
        __syncthreads();
        {
            int w = t >> 6, l = t & 63;
            int ch = l >> 5, hw = l & 31;
            float* dst = out3 + (size_t)b * DIM * HWSZ + hw0b + sub * 32 + hw;
#pragma unroll
            for (int it = 0; it < 32; ++it) {
                int c = w * 64 + it * 2 + ch;
                dst[(size_t)c * HWSZ] = E[hw][c];
            }
        }
    }
}

extern "C" void kernel_launch(void* const* d_in, const int* in_sizes, int n_in,
                              void* d_out, int out_size, void* d_ws, size_t ws_size,
                              hipStream_t stream) {
    const float* z = (const float*)d_in[0];
    const float* emb = (const float*)d_in[1];
    float* out = (float*)d_out;
    float* out0 = out;                    // encoded_flat  [65536,256]
    float* out1 = out + 16777216;         // quantized_flat[65536,256]
    float* out2 = out + 33554432;         // indices       [65536] (as float)
    float* out3 = out + 33619968;         // quantized     [16,256,64,64]

    // A-operand fp16 hi/lo scratch fills the out1 region (64 MB); out1 is
    // written afterwards by k_final_all.
    _Float16* AhF = (_Float16*)out1;
    _Float16* AlF = (_Float16*)(out1 + 8388608);

    char* ws = (char*)d_ws;
    _Float16* BhF = (_Float16*)(ws);                 // 512 KB
    _Float16* BlF = (_Float16*)(ws + 524288);        // 512 KB
    float* e_sq = (float*)(ws + 1048576);            // 4 KB
    float* pV1 = (float*)(ws + 1052672);             // 1 MB
    int* pI1 = (int*)(ws + 2101248);                 // 1 MB

    hipFuncSetAttribute((const void*)k_gemm_argmin,
                        hipFuncAttributeMaxDynamicSharedMemorySize, 131072);

    k_prep_frag<<<128, 256, 0, stream>>>(emb, BhF, BlF);
    k_esq<<<256, 256, 0, stream>>>(emb, e_sq);
    k_transpose<<<4096, 256, 0, stream>>>(z, out0, AhF, AlF);
    k_gemm_argmin<<<1024, 1024, 131072, stream>>>(AhF, AlF, BhF, BlF, e_sq, pV1, pI1);
    k_final_all<<<256, 256, 0, stream>>>(pV1, pI1, emb, out2, out1, out3);
}